// Round 7
// baseline (326.537 us; speedup 1.0000x reference)
//
#include <hip/hip_runtime.h>

typedef __bf16 bf16;
typedef __bf16 bf16x8 __attribute__((ext_vector_type(8)));
typedef float  f32x4  __attribute__((ext_vector_type(4)));
typedef float  f32x16 __attribute__((ext_vector_type(16)));
typedef unsigned int u32;

#define DIM   1024
#define NH    16
#define NKV   4
#define HD    64
#define SLEN  264
#define BTOT  64            // B*T
#define MROWS (BTOT * SLEN) // 16896
#define NQKV  1536          // 1024 q + 256 k + 256 v
#define NZ    256
#define VPAD  288           // padded key dim of vt

// ---------------- async global->LDS (wave-uniform LDS base + lane*16; global src is per-lane) ----------------
__device__ __forceinline__ void gl_lds16(const bf16* g, bf16* l) {
    __builtin_amdgcn_global_load_lds((__attribute__((address_space(1))) void*)(g),
                                     (__attribute__((address_space(3))) void*)(l),
                                     16, 0, 0);
}

// ---------------- fused prep: x cvt (16896 blk) + wcat (1536) + wo (1024) + rope (32) ----------------
__global__ void prep_misc(const float* __restrict__ x,
                          const float* __restrict__ wq, const float* __restrict__ wk,
                          const float* __restrict__ wv, const float* __restrict__ wo,
                          bf16* __restrict__ xbf, bf16* __restrict__ wcat,
                          bf16* __restrict__ wobf, float2* __restrict__ ctab) {
    int b = blockIdx.x, tid = threadIdx.x;
    if (b < 16896) {                        // x: f32 -> bf16 (16896*1024 elems)
        int i = (b * 256 + tid) * 4;
        float4 v = *(const float4*)(x + i);
        xbf[i + 0] = (bf16)v.x; xbf[i + 1] = (bf16)v.y;
        xbf[i + 2] = (bf16)v.z; xbf[i + 3] = (bf16)v.w;
        return;
    }
    int b2 = b - 16896;
    if (b2 < 1536) {                        // wcat = [wq;wk;wv] bf16
        int i = (b2 * 256 + tid) * 4;
        const float* src; int off;
        if (i < 1024 * 1024)      { src = wq; off = i; }
        else if (i < 1280 * 1024) { src = wk; off = i - 1024 * 1024; }
        else                      { src = wv; off = i - 1280 * 1024; }
        float4 v = *(const float4*)(src + off);
        wcat[i + 0] = (bf16)v.x; wcat[i + 1] = (bf16)v.y;
        wcat[i + 2] = (bf16)v.z; wcat[i + 3] = (bf16)v.w;
    } else if (b2 < 2560) {                 // wo bf16
        int i = ((b2 - 1536) * 256 + tid) * 4;
        float4 v = *(const float4*)(wo + i);
        wobf[i + 0] = (bf16)v.x; wobf[i + 1] = (bf16)v.y;
        wobf[i + 2] = (bf16)v.z; wobf[i + 3] = (bf16)v.w;
    } else {                                // rope cos/sin table: 256 x 32
        int i = (b2 - 2560) * 256 + tid;
        int s = i >> 5, d = i & 31;
        const float LN1 = 0.5756462732485115f;    // ln(10000)/16
        float pos = (d < 16) ? (float)(s >> 4) : (float)(s & 15);
        float ang = pos * expf(-(float)(d & 15) * LN1);
        float sn, cs; sincosf(ang, &sn, &cs);
        ctab[i] = make_float2(cs, sn);
    }
}

// bijective XCD-chunked block swizzle (m204): contiguous wg-chunks per XCD
__device__ __forceinline__ int xcd_swizzle(int orig, int nwg) {
    int q = nwg >> 3, r = nwg & 7;
    int xcd = orig & 7, lid = orig >> 3;
    return (xcd < r ? xcd * (q + 1) : r * (q + 1) + (xcd - r) * q) + lid;
}

// ================= 256x256 8-phase GEMM core (round-2 proven: 88.2us, 0 conflicts) =================
#define GATE2  asm volatile("s_waitcnt vmcnt(2)" ::: "memory")
#define NOGATE do {} while (0)

#define STAGE(DST, G, H, KT) do {                                              \
    gl_lds16((G) + (size_t)((H) * 128 + rs0) * DIM + (KT) * 64 + cs0 * 8,      \
             (DST) + wid * 512);                                               \
    gl_lds16((G) + (size_t)((H) * 128 + 64 + rs0) * DIM + (KT) * 64 + cs0 * 8, \
             (DST) + 4096 + wid * 512);                                        \
} while (0)

#define PHASE(Ad, Bd, AA, KS, STAGE_STMT, GATE_STMT) do {                      \
    bf16x8 af_[4], bf_[4];                                                     \
    _Pragma("unroll")                                                          \
    for (int i_ = 0; i_ < 4; i_++) {                                           \
        af_[i_] = *(const bf16x8*)((Ad) + aRdBase + i_ * 1024 + xorv[KS]);     \
        bf_[i_] = *(const bf16x8*)((Bd) + bRdBase + i_ * 1024 + xorv[KS]);     \
    }                                                                          \
    STAGE_STMT;                                                                \
    GATE_STMT;                                                                 \
    __builtin_amdgcn_s_barrier();                                              \
    asm volatile("s_waitcnt lgkmcnt(0)" ::: "memory");                         \
    __builtin_amdgcn_sched_barrier(0);                                         \
    __builtin_amdgcn_s_setprio(1);                                             \
    _Pragma("unroll")                                                          \
    for (int i_ = 0; i_ < 4; i_++)                                             \
        _Pragma("unroll")                                                      \
        for (int n_ = 0; n_ < 4; n_++)                                         \
            acc[AA][i_][n_] = __builtin_amdgcn_mfma_f32_16x16x32_bf16(         \
                af_[i_], bf_[n_], acc[AA][i_][n_], 0, 0, 0);                   \
    __builtin_amdgcn_s_setprio(0);                                             \
    __builtin_amdgcn_s_barrier();                                              \
} while (0)

__device__ __forceinline__ void gemm256_core(const bf16* __restrict__ Ag,
                                             const bf16* __restrict__ Bg,
                                             f32x4 (&acc)[2][4][4]) {
    __shared__ __align__(16) bf16 A00[128 * 64], A01[128 * 64], A10[128 * 64], A11[128 * 64];
    __shared__ __align__(16) bf16 B00[128 * 64], B01[128 * 64], B10[128 * 64], B11[128 * 64];

    const int tid  = threadIdx.x;
    const int wid  = tid >> 6, lane = tid & 63;
    const int quad = lane >> 4, r16 = lane & 15;
    const int wm = wid & 1, wn = wid >> 1;

    const int rs0 = tid >> 3;
    const int cs0 = (tid & 7) ^ (rs0 & 7);

    const int aRdBase = (wm * 64 + r16) * 64;
    const int bRdBase = ((wn & 1) * 64 + r16) * 64;
    const int xorv[2] = { (quad ^ (r16 & 7)) * 8, ((4 + quad) ^ (r16 & 7)) * 8 };

    const bf16* Bd0 = (wn & 2) ? B01 : B00;   // wave's N-half, parity 0
    const bf16* Bd1 = (wn & 2) ? B11 : B10;   // wave's N-half, parity 1

    STAGE(A00, Ag, 0, 0);
    STAGE(A01, Ag, 1, 0);
    STAGE(B00, Bg, 0, 0);
    STAGE(B01, Bg, 1, 0);
    STAGE(A10, Ag, 0, 1);
    GATE2;                                  // tile0 landed; A10<-t1 may fly
    __builtin_amdgcn_s_barrier();

#pragma unroll 1
    for (int it = 0; it < 8; ++it) {        // 2 K-tiles / iter, NT = 16
        const int t1 = 2 * it + 1;
        int t2 = 2 * it + 2; if (t2 > 15) t2 = 15;
        int t3 = 2 * it + 3; if (t3 > 15) t3 = 15;
        PHASE(A00, Bd0, 0, 0, STAGE(A11, Ag, 1, t1), NOGATE);
        PHASE(A00, Bd0, 0, 1, STAGE(B10, Bg, 0, t1), NOGATE);
        PHASE(A01, Bd0, 1, 0, STAGE(B11, Bg, 1, t1), NOGATE);
        PHASE(A01, Bd0, 1, 1, STAGE(A00, Ag, 0, t2), GATE2);   // t1 units landed
        PHASE(A10, Bd1, 0, 0, STAGE(A01, Ag, 1, t2), NOGATE);
        PHASE(A10, Bd1, 0, 1, STAGE(B00, Bg, 0, t2), NOGATE);
        PHASE(A11, Bd1, 1, 0, STAGE(B01, Bg, 1, t2), NOGATE);
        PHASE(A11, Bd1, 1, 1, STAGE(A10, Ag, 0, t3), GATE2);   // t2 units landed
    }
}

// ---------------- QKV GEMM with fused QKNorm + partial 2D-RoPE epilogue (round-5 proven) ----------------
__global__ __launch_bounds__(512) void gemm_qkv(const bf16* __restrict__ A,
                                                const bf16* __restrict__ Bw,
                                                bf16* __restrict__ out,
                                                const float* __restrict__ qw,
                                                const float* __restrict__ kw,
                                                const float2* __restrict__ ctab) {
    const int nwg = (MROWS / 256) * (NQKV / 256);   // 396
    int wg = xcd_swizzle(blockIdx.x, nwg);
    const int bm = wg / 6, bn = wg - bm * 6;

    f32x4 acc[2][4][4];
#pragma unroll
    for (int a = 0; a < 2; a++)
#pragma unroll
        for (int i = 0; i < 4; i++)
#pragma unroll
            for (int n = 0; n < 4; n++) acc[a][i][n] = (f32x4){0.f, 0.f, 0.f, 0.f};

    gemm256_core(A + (size_t)bm * 256 * DIM, Bw + (size_t)bn * 256 * DIM, acc);

    const int tid  = threadIdx.x;
    const int wid  = tid >> 6, lane = tid & 63;
    const int quad = lane >> 4, r16 = lane & 15;
    const int wm = wid & 1, wn = wid >> 1;
    const int colbase = bn * 256 + wn * 64;          // 64-aligned -> one head per wave
    const int rowb    = bm * 256 + wm * 64;

    if (bn < 5) {
        const float* w = (bn < 4) ? qw : kw;
        float wreg[4];
#pragma unroll
        for (int n = 0; n < 4; n++) wreg[n] = w[n * 16 + r16];
#pragma unroll
        for (int a = 0; a < 2; a++)
#pragma unroll
            for (int i = 0; i < 4; i++)
#pragma unroll
                for (int r = 0; r < 4; r++) {
                    float ss = 0.f;
#pragma unroll
                    for (int n = 0; n < 4; n++) ss += acc[a][i][n][r] * acc[a][i][n][r];
                    ss += __shfl_xor(ss, 1, 64);
                    ss += __shfl_xor(ss, 2, 64);
                    ss += __shfl_xor(ss, 4, 64);
                    ss += __shfl_xor(ss, 8, 64);
                    float rms = rsqrtf(ss * (1.f / 64.f) + 1e-6f);
                    float xv[4];
#pragma unroll
                    for (int n = 0; n < 4; n++) xv[n] = acc[a][i][n][r] * rms * wreg[n];
                    int gm = rowb + a * 128 + i * 16 + quad * 4 + r;
                    int s = gm % SLEN;
                    if (s < NZ) {   // partial 2D RoPE; pairs (n, n+2) are lane-local
                        float2 cs0 = ctab[s * 32 + r16];
                        float2 cs1 = ctab[s * 32 + 16 + r16];
                        float a0 = xv[0] * cs0.x - xv[2] * cs0.y;
                        float a2 = xv[2] * cs0.x + xv[0] * cs0.y;
                        float a1 = xv[1] * cs1.x - xv[3] * cs1.y;
                        float a3 = xv[3] * cs1.x + xv[1] * cs1.y;
                        xv[0] = a0; xv[1] = a1; xv[2] = a2; xv[3] = a3;
                    }
                    size_t rowoff = (size_t)gm * NQKV + colbase + r16;
#pragma unroll
                    for (int n = 0; n < 4; n++) out[rowoff + n * 16] = (bf16)xv[n];
                }
    } else {
#pragma unroll
        for (int a = 0; a < 2; a++)
#pragma unroll
            for (int i = 0; i < 4; i++)
#pragma unroll
                for (int r = 0; r < 4; r++) {
                    int gm = rowb + a * 128 + i * 16 + quad * 4 + r;
                    size_t rowoff = (size_t)gm * NQKV + colbase + r16;
#pragma unroll
                    for (int n = 0; n < 4; n++) out[rowoff + n * 16] = (bf16)acc[a][i][n][r];
                }
    }
}

// ================= 128x128 2-phase core for gemm_bt (3-4 blocks/CU, no tail) =================
#define GEMM_STAGE_PTRS(Mptr, tileRow, K, P)                                   \
    const bf16* P[4];                                                          \
    {                                                                          \
        _Pragma("unroll")                                                      \
        for (int k = 0; k < 4; k++) {                                          \
            int s = k * 256 + tid;                                             \
            int r = s >> 3, cp = s & 7;                                        \
            int c = cp ^ (r & 7);                                              \
            P[k] = (Mptr) + (size_t)((tileRow) + r) * (K) + c * 8;             \
        }                                                                      \
    }

__device__ __forceinline__ int swz(int row, int chunk) {   // LDS element offset
    return row * 64 + ((chunk ^ (row & 7)) * 8);
}

__global__ __launch_bounds__(256) void gemm_bt(const bf16* __restrict__ A,
                                               const bf16* __restrict__ Bw,
                                               float* __restrict__ Cout) {
    __shared__ __align__(16) bf16 As[128 * 64];
    __shared__ __align__(16) bf16 Bs[128 * 64];
    const int tid  = threadIdx.x;
    const int wid  = tid >> 6, lane = tid & 63;
    const int quad = lane >> 4, r16 = lane & 15;
    const int bid = blockIdx.x;
    const int g = bid / 32, rr = bid - g * 32;
    const int bm = g * 4 + (rr & 3), bn = rr >> 2;
    const int wm = wid & 1, wn = wid >> 1;

    GEMM_STAGE_PTRS(A,  bm * 128, DIM, Ap)
    GEMM_STAGE_PTRS(Bw, bn * 128, DIM, Bp)

    f32x4 acc[4][4];
#pragma unroll
    for (int i = 0; i < 4; i++)
#pragma unroll
        for (int j = 0; j < 4; j++) acc[i][j] = (f32x4){0.f, 0.f, 0.f, 0.f};

    for (int k0 = 0; k0 < DIM; k0 += 64) {
        __syncthreads();
#pragma unroll
        for (int k = 0; k < 4; k++) {
            gl_lds16(Ap[k] + k0, As + (k * 256 + wid * 64) * 8);
            gl_lds16(Bp[k] + k0, Bs + (k * 256 + wid * 64) * 8);
        }
        __syncthreads();
#pragma unroll
        for (int ks = 0; ks < 2; ks++) {
            bf16x8 a[4], b[4];
#pragma unroll
            for (int i = 0; i < 4; i++) {
                a[i] = *(const bf16x8*)&As[swz(wm * 64 + i * 16 + r16, ks * 4 + quad)];
                b[i] = *(const bf16x8*)&Bs[swz(wn * 64 + i * 16 + r16, ks * 4 + quad)];
            }
#pragma unroll
            for (int i = 0; i < 4; i++)
#pragma unroll
                for (int j = 0; j < 4; j++)
                    acc[i][j] = __builtin_amdgcn_mfma_f32_16x16x32_bf16(a[i], b[j], acc[i][j], 0, 0, 0);
        }
    }

#pragma unroll
    for (int i = 0; i < 4; i++)
#pragma unroll
        for (int j = 0; j < 4; j++)
#pragma unroll
            for (int r = 0; r < 4; r++) {
                int gm = bm * 128 + wm * 64 + i * 16 + quad * 4 + r;
                int gn = bn * 128 + wn * 64 + j * 16 + r16;
                Cout[(size_t)gm * DIM + gn] = acc[i][j][r];
            }
}

// ---------------- V transpose v2: 512 blocks (bt,kv,d-half), vectorized output side ----------------
// Block = 32 d x 264 keys. Input: coalesced bf16x8 reads of qkv V rows; transpose
// via scalar LDS writes (per-wave 2-way bank = free); output: bf16x8 LDS reads +
// 16B coalesced stores to vt (incl. zero pad to 288). LDS stride 280 (16B-aligned).
__global__ __launch_bounds__(256) void vtrans_kernel(const bf16* __restrict__ qkv,
                                                     bf16* __restrict__ vt) {
    __shared__ __align__(16) bf16 Ls[32 * 280];
    const int tid = threadIdx.x;
    const int half = blockIdx.x, kv = blockIdx.y, bt = blockIdx.z;
    // zero pad cols 264..271 (32 rows x 8 cols, one elem/thread)
    Ls[(tid >> 3) * 280 + 264 + (tid & 7)] = (bf16)0.f;
    const int part = tid >> 6;             // 0..3 (wave-uniform) -> d-octet
    const int rr   = tid & 63;
    const bf16* src = qkv + (size_t)bt * SLEN * NQKV + 1280 + kv * 64 + half * 32 + part * 8;
#pragma unroll
    for (int pass = 0; pass < 5; ++pass) {
        int row = pass * 64 + rr;
        if (row < SLEN) {
            bf16x8 v = *(const bf16x8*)(src + (size_t)row * NQKV);
#pragma unroll
            for (int j = 0; j < 8; j++) Ls[(part * 8 + j) * 280 + row] = v[j];
        }
    }
    __syncthreads();
    const int d = tid >> 3, oct = tid & 7;
    bf16* dst = vt + (size_t)((bt * 4 + kv) * 64 + half * 32 + d) * VPAD;
#pragma unroll
    for (int m = 0; m < 5; ++m) {
        int o = m * 8 + oct;               // 0..39; need 0..35 (36*8 = 288 = VPAD)
        if (o < 36) {
            bf16x8 v;
            if (o < 34) v = *(const bf16x8*)(&Ls[d * 280 + o * 8]);  // o=33 -> zeroed pad cols
            else { bf16x8 z = {}; v = z; }                            // keys 272..287
            *(bf16x8*)(dst + o * 8) = v;
        }
    }
}

// ---------------- attention v6: block-cooperative LDS K/V staging + in-register softmax ----------------
__global__ __launch_bounds__(256) void attn_kernel(const bf16* __restrict__ qkv,
                                                   const bf16* __restrict__ vt,
                                                   bf16* __restrict__ aout) {
    __shared__ __align__(16) bf16 Kb[2][64 * 64];   // [buf][key][d], chunk-XOR swizzled
    __shared__ __align__(16) bf16 Vb[2][64 * 64];   // [buf][d][key], chunk-XOR swizzled
    __shared__ float invL[4][32];

    const int tid = threadIdx.x;
    const int wid = tid >> 6, lane = tid & 63;
    const int l31 = lane & 31, hi = lane >> 5;
    const int qp = blockIdx.x;           // 0..8 (9 tiles of 32 q-rows = 288)
    const int kv = blockIdx.y, bt = blockIdx.z;
    const int h = kv * 4 + wid;

    // Q as B-operand: lane q = l31, k = s*16 + hi*8 + reg
    int q0 = qp * 32 + l31;
    int qcl = q0 < SLEN ? q0 : SLEN - 1;
    const bf16* qbase = qkv + (size_t)(bt * SLEN + qcl) * NQKV + h * HD + hi * 8;
    bf16x8 qb[4];
#pragma unroll
    for (int s = 0; s < 4; s++) qb[s] = *(const bf16x8*)(qbase + s * 16);

    const int r0  = tid >> 3;                       // 0..31
    const int r1  = r0 + 32;                        // 32..63
    const int kc0 = (tid & 7) ^ (r0 & 7);           // logical 8-elem chunk
    const bf16* kg = qkv + (size_t)bt * SLEN * NQKV + 1024 + kv * 64 + kc0 * 8;  // + keyrow*NQKV
    const bf16* vg = vt + (size_t)(bt * 4 + kv) * HD * VPAD;                      // + d*VPAD + off

#define STAGEP(PB, P64) do {                                                     \
    int kr0 = (P64) + r0; if (kr0 > SLEN - 1) kr0 = SLEN - 1;                    \
    int kr1 = (P64) + r1; if (kr1 > SLEN - 1) kr1 = SLEN - 1;                    \
    gl_lds16(kg + (size_t)kr0 * NQKV, &Kb[PB][tid * 8]);                         \
    gl_lds16(kg + (size_t)kr1 * NQKV, &Kb[PB][(tid + 256) * 8]);                 \
    int vo = (P64) + kc0 * 8; if (vo > VPAD - 8) vo = VPAD - 8;                  \
    gl_lds16(vg + (size_t)r0 * VPAD + vo, &Vb[PB][tid * 8]);                     \
    gl_lds16(vg + (size_t)r1 * VPAD + vo, &Vb[PB][(tid + 256) * 8]);             \
} while (0)

    const int xorb = l31 & 7;
    int koff[4];
#pragma unroll
    for (int s = 0; s < 4; s++) koff[s] = l31 * 64 + (((s * 2 + hi) ^ xorb) * 8);

    f32x16 oacc[2];
#pragma unroll
    for (int r = 0; r < 16; r++) { oacc[0][r] = 0.f; oacc[1][r] = 0.f; }
    float lsum = 0.f;

    STAGEP(0, 0);
    __syncthreads();

#pragma unroll 1
    for (int p = 0; p < 5; ++p) {
        const int pb = p & 1;
        if (p < 4) STAGEP(pb ^ 1, (p + 1) * 64);
        const int hmax = (p == 4) ? 1 : 2;   // keys 288..319 fully masked -> skip
        for (int hh = 0; hh < hmax; ++hh) {
            const bf16* Kp = &Kb[pb][hh * 2048];
            f32x16 sacc;
#pragma unroll
            for (int r = 0; r < 16; r++) sacc[r] = 0.f;
#pragma unroll
            for (int s = 0; s < 4; s++) {
                bf16x8 ka = *(const bf16x8*)(Kp + koff[s]);
                sacc = __builtin_amdgcn_mfma_f32_32x32x16_bf16(ka, qb[s], sacc, 0, 0, 0);
            }
            const int keyb = p * 64 + hh * 32;
            float pr[16];
#pragma unroll
            for (int r = 0; r < 16; ++r) {
                float sc = sacc[r];
                float t = sc * sc;
                float w = fmaf(t, 9.392546e-13f, -3.7570183e-7f);
                w = fmaf(t, w, 0.18033688f);
                float pv = exp2f(sc * w);
                int key = keyb + (r & 3) + 8 * (r >> 2) + 4 * hi;
                pv = (key < SLEN) ? pv : 0.f;
                pr[r] = pv;
                lsum += pv;
            }
#pragma unroll
            for (int st = 0; st < 2; st++) {
                u32 wA, wB, wC, wD;
                asm("v_cvt_pk_bf16_f32 %0, %1, %2" : "=v"(wA) : "v"(pr[st*8+0]), "v"(pr[st*8+1]));
                asm("v_cvt_pk_bf16_f32 %0, %1, %2" : "=v"(wB) : "v"(pr[st*8+2]), "v"(pr[st*8+3]));
                asm("v_cvt_pk_bf16_f32 %0, %1, %2" : "=v"(wC) : "v"(pr[st*8+4]), "v"(pr[st*8+5]));
                asm("v_cvt_pk_bf16_f32 %0, %1, %2" : "=v"(wD) : "v"(pr[st*8+6]), "v"(pr[st*8+7]));
                asm volatile("v_permlane32_swap_b32 %0, %1" : "+v"(wA), "+v"(wC));
                asm volatile("v_permlane32_swap_b32 %0, %1" : "+v"(wB), "+v"(wD));
                union { u32 u[4]; bf16x8 v; } pa;
                pa.u[0] = wA; pa.u[1] = wB; pa.u[2] = wC; pa.u[3] = wD;
#pragma unroll
                for (int dt = 0; dt < 2; dt++) {
                    bf16x8 vbf = *(const bf16x8*)(&Vb[pb][(dt * 32 + l31) * 64 +
                                         (((hh * 4 + st * 2 + hi) ^ xorb) * 8)]);
                    oacc[dt] = __builtin_amdgcn_mfma_f32_32x32x16_bf16(pa.v, vbf, oacc[dt], 0, 0, 0);
                }
            }
        }
        if (p < 4) __syncthreads();   // drains gl_lds (vmcnt) -> buf pb^1 ready; all reads of pb done
    }
#undef STAGEP

    lsum += __shfl_xor(lsum, 32, 64);
    invL[wid][l31] = 1.f / lsum;           // per-wave LDS, wave-coherent
#pragma unroll
    for (int r = 0; r < 16; ++r) {
        int qloc = (r & 3) + 8 * (r >> 2) + 4 * hi;
        int q = qp * 32 + qloc;
        if (q < SLEN) {
            float inv = invL[wid][qloc];
            size_t base = (size_t)(bt * SLEN + q) * (NH * HD) + h * HD + l31;
            aout[base]      = (bf16)(oacc[0][r] * inv);
            aout[base + 32] = (bf16)(oacc[1][r] * inv);
        }
    }
}

// ---------------- launcher (5 kernels) ----------------
extern "C" void kernel_launch(void* const* d_in, const int* in_sizes, int n_in,
                              void* d_out, int out_size, void* d_ws, size_t ws_size,
                              hipStream_t stream) {
    const float* x   = (const float*)d_in[0];
    const float* wq  = (const float*)d_in[1];
    const float* wk  = (const float*)d_in[2];
    const float* wv  = (const float*)d_in[3];
    const float* wo  = (const float*)d_in[4];
    const float* qnw = (const float*)d_in[5];
    const float* knw = (const float*)d_in[6];

    bf16* xbf  = (bf16*)d_ws;                        // 16896x1024 (reused as aout)
    bf16* wcat = xbf  + (size_t)MROWS * DIM;         // 1536x1024  [wq;wk;wv]
    bf16* wobf = wcat + (size_t)NQKV * DIM;          // 1024x1024
    bf16* qkv  = wobf + (size_t)DIM * DIM;           // 16896x1536
    bf16* vt   = qkv  + (size_t)MROWS * NQKV;        // 256x64x288
    float2* ctab = (float2*)(vt + (size_t)BTOT * NKV * HD * VPAD);  // 256x32
    bf16* aout = xbf;                                // xbf dead after gemm_qkv

    prep_misc<<<16896 + 1536 + 1024 + 32, 256, 0, stream>>>(
        x, wq, wk, wv, wo, xbf, wcat, wobf, ctab);

    gemm_qkv<<<(MROWS / 256) * (NQKV / 256), 512, 0, stream>>>(xbf, wcat, qkv, qnw, knw, ctab);
    vtrans_kernel<<<dim3(2, NKV, BTOT), 256, 0, stream>>>(qkv, vt);
    attn_kernel<<<dim3(9, NKV, BTOT), 256, 0, stream>>>(qkv, vt, aout);
    gemm_bt<<<(MROWS / 128) * (DIM / 128), 256, 0, stream>>>(aout, wobf, (float*)d_out);
}